// Round 4
// baseline (368.021 us; speedup 1.0000x reference)
//
#include <hip/hip_runtime.h>
#include <stdint.h>
#include <stddef.h>

typedef __attribute__((ext_vector_type(8))) short bf16x8;
typedef __attribute__((ext_vector_type(4))) float f32x4;
typedef __attribute__((ext_vector_type(4))) unsigned int u32x4;

#define AS1 __attribute__((address_space(1)))
#define AS3 __attribute__((address_space(3)))

__device__ __forceinline__ void gll16(const void* g, void* l) {
  __builtin_amdgcn_global_load_lds((const AS1 unsigned int*)g, (AS3 unsigned int*)l, 16, 0, 0);
}

__device__ __forceinline__ uint16_t f2bf(float f) {
  uint32_t u = __builtin_bit_cast(uint32_t, f);
  u += 0x7fffu + ((u >> 16) & 1u);
  return (uint16_t)(u >> 16);
}
__device__ __forceinline__ float bf2f(uint16_t h) {
  uint32_t u = ((uint32_t)h) << 16;
  return __builtin_bit_cast(float, u);
}

// ---------------------------------------------------------------- f32 -> bf16
__global__ void cvt_f32_bf16(const float* __restrict__ in, uint16_t* __restrict__ out, int n8) {
  int i = blockIdx.x * blockDim.x + threadIdx.x;
  if (i >= n8) return;
  float4 a = reinterpret_cast<const float4*>(in)[2 * i];
  float4 b = reinterpret_cast<const float4*>(in)[2 * i + 1];
  union { uint16_t h[8]; u32x4 v; } u;
  u.h[0] = f2bf(a.x); u.h[1] = f2bf(a.y); u.h[2] = f2bf(a.z); u.h[3] = f2bf(a.w);
  u.h[4] = f2bf(b.x); u.h[5] = f2bf(b.y); u.h[6] = f2bf(b.z); u.h[7] = f2bf(b.w);
  reinterpret_cast<u32x4*>(out)[i] = u.v;
}

// ---------------------------------------------------------------- RoPE table
__global__ void rope_table(float* __restrict__ cosT, float* __restrict__ sinT) {
  int idx = blockIdx.x * blockDim.x + threadIdx.x;  // 2048*64
  int s = idx >> 6, i = idx & 63;
  float invf = expf(-(float)i * (9.2103403719761836f / 64.0f));
  float f = (float)s * invf;
  cosT[idx] = cosf(f);
  sinT[idx] = sinf(f);
}

// ---------------------------------------------------------------- RoPE apply (in place on [2,16,2048,128] bf16)
__global__ void rope_apply(uint16_t* __restrict__ buf,
                           const float* __restrict__ cosT, const float* __restrict__ sinT) {
  int idx = blockIdx.x * blockDim.x + threadIdx.x;  // 2*16*2048*64 = 4194304
  int i = idx & 63;
  int s = (idx >> 6) & 2047;
  int bh = idx >> 17;
  size_t base = ((size_t)bh * 2048 + s) * 128;
  float x0 = bf2f(buf[base + i]);
  float x1 = bf2f(buf[base + i + 64]);
  float c = cosT[(s << 6) + i], sn = sinT[(s << 6) + i];
  buf[base + i]      = f2bf(x0 * c - x1 * sn);
  buf[base + i + 64] = f2bf(x1 * c + x0 * sn);
}

// ---------------------------------------------------------------- GEMM1: qkv = x @ Wqkv^T
// 3-stage software pipeline: 3 LDS buffers, prefetch distance 2, one raw
// s_barrier per K-step, counted vmcnt(4) so 4 loads stay in flight across the
// barrier (T3/T4 mechanism). Region proof: stage(t+2)->buf[(t+2)%3]; that
// buffer's last reader was step t-1 (barrier-ordered before step t).
__global__ __launch_bounds__(256) void gemm_qkv(
    const uint16_t* __restrict__ A,   // [4096][2048]
    const uint16_t* __restrict__ B,   // [6144][2048]
    uint16_t* __restrict__ Qb, uint16_t* __restrict__ Kb, uint16_t* __restrict__ Vt) {
  __shared__ uint16_t Ash[3][128 * 32];
  __shared__ uint16_t Bsh[3][128 * 32];
  const int t = threadIdx.x;
  const int lane = t & 63;
  const int w = t >> 6, wr = w >> 1, wc = w & 1;
  const int fr = lane & 15, fg = lane >> 4, fk = fg * 8;
  const int m0 = blockIdx.x * 128, n0 = blockIdx.y * 128;
  const int K = 2048;
  const int T = K / 32;
  const int c0 = t, c1 = t + 256;

  f32x4 acc[4][4];
#pragma unroll
  for (int i = 0; i < 4; i++)
#pragma unroll
    for (int j = 0; j < 4; j++) acc[i][j] = (f32x4)(0.0f);

#define QKV_STAGE(tile, buf)                                                        \
  {                                                                                 \
    int kt_ = (tile) * 32;                                                          \
    gll16(&A[(size_t)(m0 + (c0 >> 2)) * K + kt_ + (c0 & 3) * 8], &Ash[buf][(c0 & ~63) * 8]); \
    gll16(&A[(size_t)(m0 + (c1 >> 2)) * K + kt_ + (c1 & 3) * 8], &Ash[buf][(c1 & ~63) * 8]); \
    gll16(&B[(size_t)(n0 + (c0 >> 2)) * K + kt_ + (c0 & 3) * 8], &Bsh[buf][(c0 & ~63) * 8]); \
    gll16(&B[(size_t)(n0 + (c1 >> 2)) * K + kt_ + (c1 & 3) * 8], &Bsh[buf][(c1 & ~63) * 8]); \
  }

  QKV_STAGE(0, 0);
  QKV_STAGE(1, 1);
  asm volatile("s_waitcnt vmcnt(4)" ::: "memory");  // tile 0 landed; tile 1 in flight
  __builtin_amdgcn_s_barrier();
  asm volatile("" ::: "memory");

  for (int tl = 0; tl < T; ++tl) {
    const int cur = tl % 3;
    if (tl + 2 < T) QKV_STAGE(tl + 2, (tl + 2) % 3);
    bf16x8 af[4], bfr[4];
#pragma unroll
    for (int mi = 0; mi < 4; mi++) af[mi] = *(const bf16x8*)&Ash[cur][(wr * 64 + mi * 16 + fr) * 32 + fk];
#pragma unroll
    for (int ni = 0; ni < 4; ni++) bfr[ni] = *(const bf16x8*)&Bsh[cur][(wc * 64 + ni * 16 + fr) * 32 + fk];
    __builtin_amdgcn_s_setprio(1);
#pragma unroll
    for (int mi = 0; mi < 4; mi++)
#pragma unroll
      for (int ni = 0; ni < 4; ni++)
        acc[mi][ni] = __builtin_amdgcn_mfma_f32_16x16x32_bf16(af[mi], bfr[ni], acc[mi][ni], 0, 0, 0);
    __builtin_amdgcn_s_setprio(0);
    if (tl + 2 < T) {
      asm volatile("s_waitcnt vmcnt(4)" ::: "memory");  // tile tl+1 landed; tl+2 in flight
    } else {
      asm volatile("s_waitcnt vmcnt(0)" ::: "memory");  // tail drain
    }
    __builtin_amdgcn_s_barrier();
    asm volatile("" ::: "memory");
  }
#undef QKV_STAGE

#pragma unroll
  for (int mi = 0; mi < 4; mi++) {
#pragma unroll
    for (int ni = 0; ni < 4; ni++) {
      int ng = n0 + wc * 64 + ni * 16 + fr;
      int head = (ng >> 7) & 15, dd = ng & 127;
      if (ng < 4096) {
        uint16_t* dst = (ng < 2048) ? Qb : Kb;
#pragma unroll
        for (int r = 0; r < 4; r++) {
          int mg = m0 + wr * 64 + mi * 16 + fg * 4 + r;
          int b = mg >> 11, si = mg & 2047;
          dst[((size_t)(b * 16 + head) * 2048 + si) * 128 + dd] = f2bf(acc[mi][ni][r]);
        }
      } else {
        uint32_t h0 = f2bf(acc[mi][ni][0]), h1 = f2bf(acc[mi][ni][1]);
        uint32_t h2 = f2bf(acc[mi][ni][2]), h3 = f2bf(acc[mi][ni][3]);
        uint2 pv = make_uint2(h0 | (h1 << 16), h2 | (h3 << 16));
        int mg = m0 + wr * 64 + mi * 16 + fg * 4;
        int b = mg >> 11, si = mg & 2047;
        *(uint2*)&Vt[((size_t)(b * 16 + head) * 128 + dd) * 2048 + si] = pv;
      }
    }
  }
}

// ---------------------------------------------------------------- GEMM2: out = z @ Wo^T (f32 out), same pipeline
__global__ __launch_bounds__(256) void gemm_out_k(
    const uint16_t* __restrict__ A,   // [4096][2048] bf16 (z in [b,s,d])
    const uint16_t* __restrict__ B,   // [2048][2048] bf16 (Wo)
    float* __restrict__ C) {          // [4096][2048] f32
  __shared__ uint16_t Ash[3][128 * 32];
  __shared__ uint16_t Bsh[3][128 * 32];
  const int t = threadIdx.x;
  const int lane = t & 63;
  const int w = t >> 6, wr = w >> 1, wc = w & 1;
  const int fr = lane & 15, fg = lane >> 4, fk = fg * 8;
  const int m0 = blockIdx.x * 128, n0 = blockIdx.y * 128;
  const int K = 2048;
  const int T = K / 32;
  const int c0 = t, c1 = t + 256;

  f32x4 acc[4][4];
#pragma unroll
  for (int i = 0; i < 4; i++)
#pragma unroll
    for (int j = 0; j < 4; j++) acc[i][j] = (f32x4)(0.0f);

#define OUT_STAGE(tile, buf)                                                        \
  {                                                                                 \
    int kt_ = (tile) * 32;                                                          \
    gll16(&A[(size_t)(m0 + (c0 >> 2)) * K + kt_ + (c0 & 3) * 8], &Ash[buf][(c0 & ~63) * 8]); \
    gll16(&A[(size_t)(m0 + (c1 >> 2)) * K + kt_ + (c1 & 3) * 8], &Ash[buf][(c1 & ~63) * 8]); \
    gll16(&B[(size_t)(n0 + (c0 >> 2)) * K + kt_ + (c0 & 3) * 8], &Bsh[buf][(c0 & ~63) * 8]); \
    gll16(&B[(size_t)(n0 + (c1 >> 2)) * K + kt_ + (c1 & 3) * 8], &Bsh[buf][(c1 & ~63) * 8]); \
  }

  OUT_STAGE(0, 0);
  OUT_STAGE(1, 1);
  asm volatile("s_waitcnt vmcnt(4)" ::: "memory");
  __builtin_amdgcn_s_barrier();
  asm volatile("" ::: "memory");

  for (int tl = 0; tl < T; ++tl) {
    const int cur = tl % 3;
    if (tl + 2 < T) OUT_STAGE(tl + 2, (tl + 2) % 3);
    bf16x8 af[4], bfr[4];
#pragma unroll
    for (int mi = 0; mi < 4; mi++) af[mi] = *(const bf16x8*)&Ash[cur][(wr * 64 + mi * 16 + fr) * 32 + fk];
#pragma unroll
    for (int ni = 0; ni < 4; ni++) bfr[ni] = *(const bf16x8*)&Bsh[cur][(wc * 64 + ni * 16 + fr) * 32 + fk];
    __builtin_amdgcn_s_setprio(1);
#pragma unroll
    for (int mi = 0; mi < 4; mi++)
#pragma unroll
      for (int ni = 0; ni < 4; ni++)
        acc[mi][ni] = __builtin_amdgcn_mfma_f32_16x16x32_bf16(af[mi], bfr[ni], acc[mi][ni], 0, 0, 0);
    __builtin_amdgcn_s_setprio(0);
    if (tl + 2 < T) {
      asm volatile("s_waitcnt vmcnt(4)" ::: "memory");
    } else {
      asm volatile("s_waitcnt vmcnt(0)" ::: "memory");
    }
    __builtin_amdgcn_s_barrier();
    asm volatile("" ::: "memory");
  }
#undef OUT_STAGE

#pragma unroll
  for (int mi = 0; mi < 4; mi++) {
#pragma unroll
    for (int ni = 0; ni < 4; ni++) {
      int ng = n0 + wc * 64 + ni * 16 + fr;
#pragma unroll
      for (int r = 0; r < 4; r++) {
        int mg = m0 + wr * 64 + mi * 16 + fg * 4 + r;
        C[(size_t)mg * 2048 + ng] = acc[mi][ni][r];
      }
    }
  }
}

// ---------------------------------------------------------------- flash attention (causal)  [unchanged from round 3]
__global__ __launch_bounds__(256, 2) void attn_kernel(
    const uint16_t* __restrict__ Qb, const uint16_t* __restrict__ Kb,
    const uint16_t* __restrict__ Vt, uint16_t* __restrict__ zb) {
  __shared__ uint16_t Ksh[64 * 128];    // [kv 64][d 128], 16B-chunk xor-swizzled by (row&7)
  __shared__ uint16_t Vsh[128 * 64];    // [d 128][kv 64], 16B-chunk xor-swizzled by (d&7)
  __shared__ uint16_t Psh[4][32][72];   // per-wave P[32 q][64 kv], +8 pad

  const int t = threadIdx.x, lane = t & 63, w = t >> 6;
  const int fr = lane & 15, fg = lane >> 4, fk = fg * 8;
  const int bx = blockIdx.x, bh = blockIdx.y;
  const int qt = (bh & 16) ? (15 - bx) : bx;   // CU-pair balance: qt + qt' = 15
  const int q0 = qt * 128;
  const size_t hbase = (size_t)bh * 2048 * 128;
  const float scale2 = 0.08838834764831845f * 1.4426950408889634f;  // * log2(e)

  bf16x8 qf[2][4];
#pragma unroll
  for (int qs = 0; qs < 2; ++qs)
#pragma unroll
    for (int dc = 0; dc < 4; ++dc)
      qf[qs][dc] = *(const bf16x8*)&Qb[hbase + (size_t)(q0 + w * 32 + qs * 16 + fr) * 128 + dc * 32 + fk];

  f32x4 oacc[2][8];
#pragma unroll
  for (int qs = 0; qs < 2; ++qs)
#pragma unroll
    for (int i = 0; i < 8; i++) oacc[qs][i] = (f32x4)(0.0f);
  float mrow[2][4], lrow[2][4];
#pragma unroll
  for (int qs = 0; qs < 2; ++qs)
#pragma unroll
    for (int r = 0; r < 4; r++) { mrow[qs][r] = -1e30f; lrow[qs][r] = 0.0f; }

  const int ktiles = 2 * qt + 2;
  for (int kt = 0; kt < ktiles; ++kt) {
    __syncthreads();
    const uint16_t* Kg = Kb + hbase + (size_t)kt * 64 * 128;
    const uint16_t* Vg = Vt + hbase + (size_t)kt * 64;
#pragma unroll
    for (int i = 0; i < 4; i++) {
      int c = t + i * 256;
      { int row = c >> 4, cc = c & 15, scc = cc ^ (row & 7);
        gll16(&Kg[row * 128 + scc * 8], &Ksh[(c & ~63) * 8]); }
      { int r = c >> 3, cc = c & 7, scc = cc ^ (r & 7);
        gll16(&Vg[(size_t)r * 2048 + scc * 8], &Vsh[(c & ~63) * 8]); }
    }
    __syncthreads();

    const int kv_base = kt * 64;
    if (kv_base <= q0 + w * 32 + 31) {
      f32x4 sacc[2][4];
#pragma unroll
      for (int qs = 0; qs < 2; ++qs)
#pragma unroll
        for (int kv16 = 0; kv16 < 4; ++kv16) sacc[qs][kv16] = (f32x4)(0.0f);
      __builtin_amdgcn_s_setprio(1);
#pragma unroll
      for (int kv16 = 0; kv16 < 4; ++kv16) {
        int row = kv16 * 16 + fr;
#pragma unroll
        for (int dc = 0; dc < 4; ++dc) {
          int sc = (dc * 4 + fg) ^ (row & 7);
          bf16x8 kf = *(const bf16x8*)&Ksh[row * 128 + sc * 8];
          sacc[0][kv16] = __builtin_amdgcn_mfma_f32_16x16x32_bf16(qf[0][dc], kf, sacc[0][kv16], 0, 0, 0);
          sacc[1][kv16] = __builtin_amdgcn_mfma_f32_16x16x32_bf16(qf[1][dc], kf, sacc[1][kv16], 0, 0, 0);
        }
      }
      __builtin_amdgcn_s_setprio(0);

      const bool need_mask = (kv_base + 63 > q0 + w * 32);
      float alpha[2][4];
#pragma unroll
      for (int qs = 0; qs < 2; ++qs) {
#pragma unroll
        for (int r = 0; r < 4; ++r) {
          int rowg = q0 + w * 32 + qs * 16 + fg * 4 + r;
          float s0 = sacc[qs][0][r] * scale2, s1 = sacc[qs][1][r] * scale2;
          float s2 = sacc[qs][2][r] * scale2, s3 = sacc[qs][3][r] * scale2;
          if (need_mask) {
            if (kv_base + 0 * 16 + fr > rowg) s0 = -1e30f;
            if (kv_base + 1 * 16 + fr > rowg) s1 = -1e30f;
            if (kv_base + 2 * 16 + fr > rowg) s2 = -1e30f;
            if (kv_base + 3 * 16 + fr > rowg) s3 = -1e30f;
          }
          float mx = fmaxf(fmaxf(s0, s1), fmaxf(s2, s3));
#pragma unroll
          for (int off = 1; off < 16; off <<= 1) mx = fmaxf(mx, __shfl_xor(mx, off, 64));
          float mnew = fmaxf(mrow[qs][r], mx);
          alpha[qs][r] = exp2f(mrow[qs][r] - mnew);
          mrow[qs][r] = mnew;
          float p0 = exp2f(s0 - mnew), p1 = exp2f(s1 - mnew);
          float p2 = exp2f(s2 - mnew), p3 = exp2f(s3 - mnew);
          float ps = p0 + p1 + p2 + p3;
#pragma unroll
          for (int off = 1; off < 16; off <<= 1) ps += __shfl_xor(ps, off, 64);
          lrow[qs][r] = lrow[qs][r] * alpha[qs][r] + ps;
          int ql = qs * 16 + fg * 4 + r;
          Psh[w][ql][0 * 16 + fr] = f2bf(p0);
          Psh[w][ql][1 * 16 + fr] = f2bf(p1);
          Psh[w][ql][2 * 16 + fr] = f2bf(p2);
          Psh[w][ql][3 * 16 + fr] = f2bf(p3);
        }
#pragma unroll
        for (int i = 0; i < 8; i++)
#pragma unroll
          for (int r = 0; r < 4; r++) oacc[qs][i][r] *= alpha[qs][r];
      }

      asm volatile("s_waitcnt lgkmcnt(0)" ::: "memory");

      __builtin_amdgcn_s_setprio(1);
#pragma unroll
      for (int kc = 0; kc < 2; ++kc) {
        bf16x8 pf0 = *(const bf16x8*)&Psh[w][fr][kc * 32 + fk];
        bf16x8 pf1 = *(const bf16x8*)&Psh[w][16 + fr][kc * 32 + fk];
#pragma unroll
        for (int n8 = 0; n8 < 8; ++n8) {
          int d = n8 * 16 + fr;
          bf16x8 vf = *(const bf16x8*)((const char*)Vsh +
                        d * 128 + (((kc * 4 + fg) ^ (d & 7)) * 16));
          oacc[0][n8] = __builtin_amdgcn_mfma_f32_16x16x32_bf16(pf0, vf, oacc[0][n8], 0, 0, 0);
          oacc[1][n8] = __builtin_amdgcn_mfma_f32_16x16x32_bf16(pf1, vf, oacc[1][n8], 0, 0, 0);
        }
      }
      __builtin_amdgcn_s_setprio(0);
    }
  }

  const int b = bh >> 4, h = bh & 15;
#pragma unroll
  for (int qs = 0; qs < 2; ++qs)
#pragma unroll
    for (int n8 = 0; n8 < 8; ++n8)
#pragma unroll
      for (int r = 0; r < 4; ++r) {
        int rowg = q0 + w * 32 + qs * 16 + fg * 4 + r;
        int d = n8 * 16 + fr;
        float o = oacc[qs][n8][r] / lrow[qs][r];
        zb[((size_t)b * 2048 + rowg) * 2048 + h * 128 + d] = f2bf(o);
      }
}

// ---------------------------------------------------------------- launch
extern "C" void kernel_launch(void* const* d_in, const int* in_sizes, int n_in,
                              void* d_out, int out_size, void* d_ws, size_t ws_size,
                              hipStream_t stream) {
  const float* x    = (const float*)d_in[0];
  const float* Wqkv = (const float*)d_in[1];
  const float* Wo   = (const float*)d_in[2];
  float* out = (float*)d_out;
  char* ws = (char*)d_ws;

  uint16_t* Qb    = (uint16_t*)(ws + 0);            // 16 MB
  uint16_t* Kb    = (uint16_t*)(ws + 16777216);     // 16 MB
  uint16_t* Vt    = (uint16_t*)(ws + 33554432);     // 16 MB  [b,h,128,2048]
  uint16_t* xb    = (uint16_t*)(ws + 50331648);     // 16 MB (dead after gemm_qkv)
  uint16_t* zb    = (uint16_t*)(ws + 50331648);     // alias xb
  uint16_t* wqkvb = (uint16_t*)(ws + 67108864);     // 24 MB
  uint16_t* wob   = (uint16_t*)(ws + 92274688);     //  8 MB
  float*    cosT  = (float*)   (ws + 100663296);
  float*    sinT  = (float*)   (ws + 101187584);

  cvt_f32_bf16<<<4096, 256, 0, stream>>>(x, xb, 8388608 / 8);
  cvt_f32_bf16<<<6144, 256, 0, stream>>>(Wqkv, wqkvb, 12582912 / 8);
  cvt_f32_bf16<<<2048, 256, 0, stream>>>(Wo, wob, 4194304 / 8);
  rope_table<<<512, 256, 0, stream>>>(cosT, sinT);

  gemm_qkv<<<dim3(32, 48), 256, 0, stream>>>(xb, wqkvb, Qb, Kb, Vt);

  rope_apply<<<16384, 256, 0, stream>>>(Qb, cosT, sinT);
  rope_apply<<<16384, 256, 0, stream>>>(Kb, cosT, sinT);

  attn_kernel<<<dim3(16, 32), 256, 0, stream>>>(Qb, Kb, Vt, zb);

  gemm_out_k<<<dim3(32, 16), 256, 0, stream>>>(zb, wob, out);
}

// Round 6
// 340.191 us; speedup vs baseline: 1.0818x; 1.0818x over previous
//
#include <hip/hip_runtime.h>
#include <stdint.h>
#include <stddef.h>

typedef __attribute__((ext_vector_type(8))) short bf16x8;
typedef __attribute__((ext_vector_type(4))) float f32x4;
typedef __attribute__((ext_vector_type(16))) float f32x16;
typedef __attribute__((ext_vector_type(4))) unsigned int u32x4;

#define AS1 __attribute__((address_space(1)))
#define AS3 __attribute__((address_space(3)))

__device__ __forceinline__ void gll16(const void* g, void* l) {
  __builtin_amdgcn_global_load_lds((const AS1 unsigned int*)g, (AS3 unsigned int*)l, 16, 0, 0);
}

__device__ __forceinline__ uint16_t f2bf(float f) {
  uint32_t u = __builtin_bit_cast(uint32_t, f);
  u += 0x7fffu + ((u >> 16) & 1u);
  return (uint16_t)(u >> 16);
}
__device__ __forceinline__ float bf2f(uint16_t h) {
  uint32_t u = ((uint32_t)h) << 16;
  return __builtin_bit_cast(float, u);
}
__device__ __forceinline__ uint32_t pack2bf(float lo, float hi) {
  return (uint32_t)f2bf(lo) | ((uint32_t)f2bf(hi) << 16);
}

// ---------------------------------------------------------------- f32 -> bf16
__global__ void cvt_f32_bf16(const float* __restrict__ in, uint16_t* __restrict__ out, int n8) {
  int i = blockIdx.x * blockDim.x + threadIdx.x;
  if (i >= n8) return;
  float4 a = reinterpret_cast<const float4*>(in)[2 * i];
  float4 b = reinterpret_cast<const float4*>(in)[2 * i + 1];
  union { uint16_t h[8]; u32x4 v; } u;
  u.h[0] = f2bf(a.x); u.h[1] = f2bf(a.y); u.h[2] = f2bf(a.z); u.h[3] = f2bf(a.w);
  u.h[4] = f2bf(b.x); u.h[5] = f2bf(b.y); u.h[6] = f2bf(b.z); u.h[7] = f2bf(b.w);
  reinterpret_cast<u32x4*>(out)[i] = u.v;
}

// ---------------------------------------------------------------- RoPE table
__global__ void rope_table(float* __restrict__ cosT, float* __restrict__ sinT) {
  int idx = blockIdx.x * blockDim.x + threadIdx.x;  // 2048*64
  int s = idx >> 6, i = idx & 63;
  float invf = expf(-(float)i * (9.2103403719761836f / 64.0f));
  float f = (float)s * invf;
  cosT[idx] = cosf(f);
  sinT[idx] = sinf(f);
}

// ---------------------------------------------------------------- RoPE apply (in place on [2,16,2048,128] bf16)
__global__ void rope_apply(uint16_t* __restrict__ buf,
                           const float* __restrict__ cosT, const float* __restrict__ sinT) {
  int idx = blockIdx.x * blockDim.x + threadIdx.x;  // 2*16*2048*64 = 4194304
  int i = idx & 63;
  int s = (idx >> 6) & 2047;
  int bh = idx >> 17;
  size_t base = ((size_t)bh * 2048 + s) * 128;
  float x0 = bf2f(buf[base + i]);
  float x1 = bf2f(buf[base + i + 64]);
  float c = cosT[(s << 6) + i], sn = sinT[(s << 6) + i];
  buf[base + i]      = f2bf(x0 * c - x1 * sn);
  buf[base + i + 64] = f2bf(x1 * c + x0 * sn);
}

// ---------------------------------------------------------------- GEMM1: qkv = x @ Wqkv^T
__global__ __launch_bounds__(256) void gemm_qkv(
    const uint16_t* __restrict__ A,   // [4096][2048]
    const uint16_t* __restrict__ B,   // [6144][2048]
    uint16_t* __restrict__ Qb, uint16_t* __restrict__ Kb, uint16_t* __restrict__ Vt) {
  __shared__ uint16_t Ash[3][128 * 32];
  __shared__ uint16_t Bsh[3][128 * 32];
  const int t = threadIdx.x;
  const int lane = t & 63;
  const int w = t >> 6, wr = w >> 1, wc = w & 1;
  const int fr = lane & 15, fg = lane >> 4, fk = fg * 8;
  const int m0 = blockIdx.x * 128, n0 = blockIdx.y * 128;
  const int K = 2048;
  const int T = K / 32;
  const int c0 = t, c1 = t + 256;

  f32x4 acc[4][4];
#pragma unroll
  for (int i = 0; i < 4; i++)
#pragma unroll
    for (int j = 0; j < 4; j++) acc[i][j] = (f32x4)(0.0f);

#define QKV_STAGE(tile, buf)                                                        \
  {                                                                                 \
    int kt_ = (tile) * 32;                                                          \
    gll16(&A[(size_t)(m0 + (c0 >> 2)) * K + kt_ + (c0 & 3) * 8], &Ash[buf][(c0 & ~63) * 8]); \
    gll16(&A[(size_t)(m0 + (c1 >> 2)) * K + kt_ + (c1 & 3) * 8], &Ash[buf][(c1 & ~63) * 8]); \
    gll16(&B[(size_t)(n0 + (c0 >> 2)) * K + kt_ + (c0 & 3) * 8], &Bsh[buf][(c0 & ~63) * 8]); \
    gll16(&B[(size_t)(n0 + (c1 >> 2)) * K + kt_ + (c1 & 3) * 8], &Bsh[buf][(c1 & ~63) * 8]); \
  }

  QKV_STAGE(0, 0);
  QKV_STAGE(1, 1);
  asm volatile("s_waitcnt vmcnt(4)" ::: "memory");
  __builtin_amdgcn_s_barrier();
  asm volatile("" ::: "memory");

  for (int tl = 0; tl < T; ++tl) {
    const int cur = tl % 3;
    if (tl + 2 < T) QKV_STAGE(tl + 2, (tl + 2) % 3);
    bf16x8 af[4], bfr[4];
#pragma unroll
    for (int mi = 0; mi < 4; mi++) af[mi] = *(const bf16x8*)&Ash[cur][(wr * 64 + mi * 16 + fr) * 32 + fk];
#pragma unroll
    for (int ni = 0; ni < 4; ni++) bfr[ni] = *(const bf16x8*)&Bsh[cur][(wc * 64 + ni * 16 + fr) * 32 + fk];
    __builtin_amdgcn_s_setprio(1);
#pragma unroll
    for (int mi = 0; mi < 4; mi++)
#pragma unroll
      for (int ni = 0; ni < 4; ni++)
        acc[mi][ni] = __builtin_amdgcn_mfma_f32_16x16x32_bf16(af[mi], bfr[ni], acc[mi][ni], 0, 0, 0);
    __builtin_amdgcn_s_setprio(0);
    if (tl + 2 < T) {
      asm volatile("s_waitcnt vmcnt(4)" ::: "memory");
    } else {
      asm volatile("s_waitcnt vmcnt(0)" ::: "memory");
    }
    __builtin_amdgcn_s_barrier();
    asm volatile("" ::: "memory");
  }
#undef QKV_STAGE

#pragma unroll
  for (int mi = 0; mi < 4; mi++) {
#pragma unroll
    for (int ni = 0; ni < 4; ni++) {
      int ng = n0 + wc * 64 + ni * 16 + fr;
      int head = (ng >> 7) & 15, dd = ng & 127;
      if (ng < 4096) {
        uint16_t* dst = (ng < 2048) ? Qb : Kb;
#pragma unroll
        for (int r = 0; r < 4; r++) {
          int mg = m0 + wr * 64 + mi * 16 + fg * 4 + r;
          int b = mg >> 11, si = mg & 2047;
          dst[((size_t)(b * 16 + head) * 2048 + si) * 128 + dd] = f2bf(acc[mi][ni][r]);
        }
      } else {
        uint2 pv = make_uint2(pack2bf(acc[mi][ni][0], acc[mi][ni][1]),
                              pack2bf(acc[mi][ni][2], acc[mi][ni][3]));
        int mg = m0 + wr * 64 + mi * 16 + fg * 4;
        int b = mg >> 11, si = mg & 2047;
        *(uint2*)&Vt[((size_t)(b * 16 + head) * 128 + dd) * 2048 + si] = pv;
      }
    }
  }
}

// ---------------------------------------------------------------- GEMM2: out = z @ Wo^T (f32 out)
__global__ __launch_bounds__(256) void gemm_out_k(
    const uint16_t* __restrict__ A,   // [4096][2048] bf16 (z in [b,s,d])
    const uint16_t* __restrict__ B,   // [2048][2048] bf16 (Wo)
    float* __restrict__ C) {          // [4096][2048] f32
  __shared__ uint16_t Ash[3][128 * 32];
  __shared__ uint16_t Bsh[3][128 * 32];
  const int t = threadIdx.x;
  const int lane = t & 63;
  const int w = t >> 6, wr = w >> 1, wc = w & 1;
  const int fr = lane & 15, fg = lane >> 4, fk = fg * 8;
  const int m0 = blockIdx.x * 128, n0 = blockIdx.y * 128;
  const int K = 2048;
  const int T = K / 32;
  const int c0 = t, c1 = t + 256;

  f32x4 acc[4][4];
#pragma unroll
  for (int i = 0; i < 4; i++)
#pragma unroll
    for (int j = 0; j < 4; j++) acc[i][j] = (f32x4)(0.0f);

#define OUT_STAGE(tile, buf)                                                        \
  {                                                                                 \
    int kt_ = (tile) * 32;                                                          \
    gll16(&A[(size_t)(m0 + (c0 >> 2)) * K + kt_ + (c0 & 3) * 8], &Ash[buf][(c0 & ~63) * 8]); \
    gll16(&A[(size_t)(m0 + (c1 >> 2)) * K + kt_ + (c1 & 3) * 8], &Ash[buf][(c1 & ~63) * 8]); \
    gll16(&B[(size_t)(n0 + (c0 >> 2)) * K + kt_ + (c0 & 3) * 8], &Bsh[buf][(c0 & ~63) * 8]); \
    gll16(&B[(size_t)(n0 + (c1 >> 2)) * K + kt_ + (c1 & 3) * 8], &Bsh[buf][(c1 & ~63) * 8]); \
  }

  OUT_STAGE(0, 0);
  OUT_STAGE(1, 1);
  asm volatile("s_waitcnt vmcnt(4)" ::: "memory");
  __builtin_amdgcn_s_barrier();
  asm volatile("" ::: "memory");

  for (int tl = 0; tl < T; ++tl) {
    const int cur = tl % 3;
    if (tl + 2 < T) OUT_STAGE(tl + 2, (tl + 2) % 3);
    bf16x8 af[4], bfr[4];
#pragma unroll
    for (int mi = 0; mi < 4; mi++) af[mi] = *(const bf16x8*)&Ash[cur][(wr * 64 + mi * 16 + fr) * 32 + fk];
#pragma unroll
    for (int ni = 0; ni < 4; ni++) bfr[ni] = *(const bf16x8*)&Bsh[cur][(wc * 64 + ni * 16 + fr) * 32 + fk];
    __builtin_amdgcn_s_setprio(1);
#pragma unroll
    for (int mi = 0; mi < 4; mi++)
#pragma unroll
      for (int ni = 0; ni < 4; ni++)
        acc[mi][ni] = __builtin_amdgcn_mfma_f32_16x16x32_bf16(af[mi], bfr[ni], acc[mi][ni], 0, 0, 0);
    __builtin_amdgcn_s_setprio(0);
    if (tl + 2 < T) {
      asm volatile("s_waitcnt vmcnt(4)" ::: "memory");
    } else {
      asm volatile("s_waitcnt vmcnt(0)" ::: "memory");
    }
    __builtin_amdgcn_s_barrier();
    asm volatile("" ::: "memory");
  }
#undef OUT_STAGE

#pragma unroll
  for (int mi = 0; mi < 4; mi++) {
#pragma unroll
    for (int ni = 0; ni < 4; ni++) {
      int ng = n0 + wc * 64 + ni * 16 + fr;
#pragma unroll
      for (int r = 0; r < 4; r++) {
        int mg = m0 + wr * 64 + mi * 16 + fg * 4 + r;
        C[(size_t)mg * 2048 + ng] = acc[mi][ni][r];
      }
    }
  }
}

// ---------------------------------------------------------------- flash attention (causal), swapped 32x32 + in-reg softmax
// Swapped QK^T (mfma(K,Q), 32x32x16): S^T layout -> q = lane&31, kv = (reg&3)+8*(reg>>2)+4*hi.
// P redistribution for PV via direction-unambiguous __shfl_xor(.,32) + hi-select
// (replaces permlane32_swap whose swap direction was the round-5 correctness bug candidate).
__device__ __forceinline__ bf16x8 mk_pa(uint32_t p0, uint32_t p1, uint32_t p2, uint32_t p3, int hi) {
  // own half holds kv {4hi+0,1},{4hi+2,3},{8+4hi+0,1},{8+4hi+2,3} in p0..p3.
  // target: 8 consecutive kv = [hi*8 .. hi*8+7].
  uint32_t x0 = (uint32_t)__shfl_xor((int)p0, 32, 64);
  uint32_t x1 = (uint32_t)__shfl_xor((int)p1, 32, 64);
  uint32_t x2 = (uint32_t)__shfl_xor((int)p2, 32, 64);
  uint32_t x3 = (uint32_t)__shfl_xor((int)p3, 32, 64);
  u32x4 v;
  v[0] = hi ? x2 : p0;   // kv {0,1} | {8,9}
  v[1] = hi ? x3 : p1;   // kv {2,3} | {10,11}
  v[2] = hi ? p2 : x0;   // kv {4,5} | {12,13}
  v[3] = hi ? p3 : x1;   // kv {6,7} | {14,15}
  return __builtin_bit_cast(bf16x8, v);
}

__global__ __launch_bounds__(256, 3) void attn_kernel(
    const uint16_t* __restrict__ Qb, const uint16_t* __restrict__ Kb,
    const uint16_t* __restrict__ Vt, uint16_t* __restrict__ zb) {
  __shared__ uint16_t Ksh[64 * 128];    // [kv 64][d 128], 16B-chunk xor-swizzled by (kv&7)
  __shared__ uint16_t Vsh[128 * 64];    // [d 128][kv 64], 16B-chunk xor-swizzled by (d&7)

  const int t = threadIdx.x, lane = t & 63, w = t >> 6;
  const int l31 = lane & 31, hi = lane >> 5;
  const int bx = blockIdx.x, bh = blockIdx.y;
  const int qt = (bh & 16) ? (15 - bx) : bx;   // CU-pair balance: qt + qt' = 15
  const int q0 = qt * 128;
  const int qg = q0 + w * 32 + l31;            // this lane's q row (S^T layout)
  const size_t hbase = (size_t)bh * 2048 * 128;
  const float scale2 = 0.08838834764831845f * 1.4426950408889634f;  // * log2(e)

  // Q fragments (B operand): B[q=l31][k = dc*16 + hi*8 + j]
  bf16x8 qf[8];
#pragma unroll
  for (int dc = 0; dc < 8; ++dc)
    qf[dc] = *(const bf16x8*)&Qb[hbase + (size_t)qg * 128 + dc * 16 + hi * 8];

  f32x16 oacc[4];
#pragma unroll
  for (int i = 0; i < 4; i++) oacc[i] = (f32x16)(0.0f);
  float mrow = -1e30f, lrow = 0.0f;

  const int ktiles = 2 * qt + 2;
  for (int kt = 0; kt < ktiles; ++kt) {
    __syncthreads();
    const uint16_t* Kg = Kb + hbase + (size_t)kt * 64 * 128;
    const uint16_t* Vg = Vt + hbase + (size_t)kt * 64;
#pragma unroll
    for (int i = 0; i < 4; i++) {
      int c = t + i * 256;
      { int row = c >> 4, cc = c & 15, scc = cc ^ (row & 7);
        gll16(&Kg[row * 128 + scc * 8], &Ksh[(c & ~63) * 8]); }
      { int r = c >> 3, cc = c & 7, scc = cc ^ (r & 7);
        gll16(&Vg[(size_t)r * 2048 + scc * 8], &Vsh[(c & ~63) * 8]); }
    }
    __syncthreads();

    const int kv_base = kt * 64;
    if (kv_base <= q0 + w * 32 + 31) {   // wave has at least one unmasked row
      // ---- QK^T swapped: S^T[kv 32][q 32] x2
      f32x16 s0 = (f32x16)(0.0f), s1 = (f32x16)(0.0f);
      __builtin_amdgcn_s_setprio(1);
#pragma unroll
      for (int dc = 0; dc < 8; ++dc) {
        int ch = dc * 2 + hi;
        bf16x8 k0 = *(const bf16x8*)&Ksh[l31 * 128 + ((ch ^ (l31 & 7)) * 8)];
        bf16x8 k1 = *(const bf16x8*)&Ksh[(32 + l31) * 128 + ((ch ^ (l31 & 7)) * 8)];
        s0 = __builtin_amdgcn_mfma_f32_32x32x16_bf16(k0, qf[dc], s0, 0, 0, 0);
        s1 = __builtin_amdgcn_mfma_f32_32x32x16_bf16(k1, qf[dc], s1, 0, 0, 0);
      }
      __builtin_amdgcn_s_setprio(0);

      // ---- scale + causal mask, in place (kv = kv_base + T*32 + (reg&3)+8*(reg>>2)+4*hi)
      const bool need_mask = (kv_base + 63 > q0 + w * 32);
#pragma unroll
      for (int reg = 0; reg < 16; ++reg) {
        int koff = (reg & 3) + 8 * (reg >> 2) + 4 * hi;
        float a0 = s0[reg] * scale2, a1 = s1[reg] * scale2;
        if (need_mask) {
          if (kv_base + koff > qg) a0 = -1e30f;
          if (kv_base + 32 + koff > qg) a1 = -1e30f;
        }
        s0[reg] = a0; s1[reg] = a1;
      }

      // ---- row max: in-lane 32 + cross-half (shfl_xor: direction-safe)
      float pmax = -1e30f;
#pragma unroll
      for (int reg = 0; reg < 16; ++reg) pmax = fmaxf(pmax, fmaxf(s0[reg], s1[reg]));
      pmax = fmaxf(pmax, __shfl_xor(pmax, 32, 64));

      // ---- defer-max (T13): skip rescale when growth <= 8 (log2 space)
      bool defer = __all(pmax <= mrow + 8.0f);
      if (!defer) {
        float mnew = fmaxf(mrow, pmax);
        float al = exp2f(mrow - mnew);
        lrow *= al;
#pragma unroll
        for (int reg = 0; reg < 16; ++reg) {
          int src = (reg & 3) + 8 * (reg >> 2) + 4 * hi;
          float ar = __shfl(al, src, 64);
#pragma unroll
          for (int n = 0; n < 4; ++n) oacc[n][reg] *= ar;
        }
        mrow = mnew;
      }

      // ---- P = exp2(s - mrow), row sum, pack to bf16 pairs
      float ps = 0.0f;
      uint32_t pk0[8], pk1[8];
#pragma unroll
      for (int i = 0; i < 8; ++i) {
        float a = exp2f(s0[2 * i] - mrow), b = exp2f(s0[2 * i + 1] - mrow);
        ps += a + b;
        pk0[i] = pack2bf(a, b);
        float c = exp2f(s1[2 * i] - mrow), d = exp2f(s1[2 * i + 1] - mrow);
        ps += c + d;
        pk1[i] = pack2bf(c, d);
      }
      ps += __shfl_xor(ps, 32, 64);
      lrow += ps;

      // ---- P redistribution -> PV A-frags (kv contiguous per half)
      bf16x8 pa[4];
      pa[0] = mk_pa(pk0[0], pk0[1], pk0[2], pk0[3], hi);
      pa[1] = mk_pa(pk0[4], pk0[5], pk0[6], pk0[7], hi);
      pa[2] = mk_pa(pk1[0], pk1[1], pk1[2], pk1[3], hi);
      pa[3] = mk_pa(pk1[4], pk1[5], pk1[6], pk1[7], hi);

      // ---- PV: O[q 32][d 128] += P[32][64] * V^T, 4 k-slices x 4 d-tiles
      __builtin_amdgcn_s_setprio(1);
#pragma unroll
      for (int ksl = 0; ksl < 4; ++ksl) {
        int ch = ksl * 2 + hi;
#pragma unroll
        for (int n = 0; n < 4; ++n) {
          int d = n * 32 + l31;
          bf16x8 vf = *(const bf16x8*)&Vsh[d * 64 + ((ch ^ (d & 7)) * 8)];
          oacc[n] = __builtin_amdgcn_mfma_f32_32x32x16_bf16(pa[ksl], vf, oacc[n], 0, 0, 0);
        }
      }
      __builtin_amdgcn_s_setprio(0);
    }
  }

  // ---- normalize + write z in [b, s, h*128+d]
  const int b = bh >> 4, h = bh & 15;
#pragma unroll
  for (int reg = 0; reg < 16; ++reg) {
    int rloc = (reg & 3) + 8 * (reg >> 2) + 4 * hi;
    float linv = 1.0f / __shfl(lrow, rloc, 64);
    int rowg = q0 + w * 32 + rloc;
    size_t base = ((size_t)b * 2048 + rowg) * 2048 + h * 128 + l31;
#pragma unroll
    for (int n = 0; n < 4; ++n)
      zb[base + n * 32] = f2bf(oacc[n][reg] * linv);
  }
}

// ---------------------------------------------------------------- launch
extern "C" void kernel_launch(void* const* d_in, const int* in_sizes, int n_in,
                              void* d_out, int out_size, void* d_ws, size_t ws_size,
                              hipStream_t stream) {
  const float* x    = (const float*)d_in[0];
  const float* Wqkv = (const float*)d_in[1];
  const float* Wo   = (const float*)d_in[2];
  float* out = (float*)d_out;
  char* ws = (char*)d_ws;

  uint16_t* Qb    = (uint16_t*)(ws + 0);            // 16 MB
  uint16_t* Kb    = (uint16_t*)(ws + 16777216);     // 16 MB
  uint16_t* Vt    = (uint16_t*)(ws + 33554432);     // 16 MB  [b,h,128,2048]
  uint16_t* xb    = (uint16_t*)(ws + 50331648);     // 16 MB (dead after gemm_qkv)
  uint16_t* zb    = (uint16_t*)(ws + 50331648);     // alias xb
  uint16_t* wqkvb = (uint16_t*)(ws + 67108864);     // 24 MB
  uint16_t* wob   = (uint16_t*)(ws + 92274688);     //  8 MB
  float*    cosT  = (float*)   (ws + 100663296);
  float*    sinT  = (float*)   (ws + 101187584);

  cvt_f32_bf16<<<4096, 256, 0, stream>>>(x, xb, 8388608 / 8);
  cvt_f32_bf16<<<6144, 256, 0, stream>>>(Wqkv, wqkvb, 12582912 / 8);
  cvt_f32_bf16<<<2048, 256, 0, stream>>>(Wo, wob, 4194304 / 8);
  rope_table<<<512, 256, 0, stream>>>(cosT, sinT);

  gemm_qkv<<<dim3(32, 48), 256, 0, stream>>>(xb, wqkvb, Qb, Kb, Vt);

  rope_apply<<<16384, 256, 0, stream>>>(Qb, cosT, sinT);
  rope_apply<<<16384, 256, 0, stream>>>(Kb, cosT, sinT);

  attn_kernel<<<dim3(16, 32), 256, 0, stream>>>(Qb, Kb, Vt, zb);

  gemm_out_k<<<dim3(32, 16), 256, 0, stream>>>(zb, wob, out);
}